// Round 1
// baseline (387.277 us; speedup 1.0000x reference)
//
#include <hip/hip_runtime.h>
#include <hip/hip_bf16.h>
#include <stdint.h>

using bf16 = __hip_bfloat16;

#define SCALE 0.17677669529663687f   // 32^-0.5

typedef short short8 __attribute__((ext_vector_type(8)));
typedef float f32x4 __attribute__((ext_vector_type(4)));

__device__ __forceinline__ float bf2f(bf16 v) { return __bfloat162float(v); }

__device__ __forceinline__ unsigned short f2bf(float f) {
    unsigned int u = __float_as_uint(f);
    unsigned int r = u + 0x7fffu + ((u >> 16) & 1u);   // RNE; inputs never NaN/Inf
    return (unsigned short)(r >> 16);
}

// load 8 consecutive bf16 (16B-aligned) -> 8 floats
__device__ __forceinline__ void load8bf(const bf16* p, float* f) {
    uint4 u = *reinterpret_cast<const uint4*>(p);
    f[0] = __uint_as_float(u.x << 16); f[1] = __uint_as_float(u.x & 0xffff0000u);
    f[2] = __uint_as_float(u.y << 16); f[3] = __uint_as_float(u.y & 0xffff0000u);
    f[4] = __uint_as_float(u.z << 16); f[5] = __uint_as_float(u.z & 0xffff0000u);
    f[6] = __uint_as_float(u.w << 16); f[7] = __uint_as_float(u.w & 0xffff0000u);
}

__device__ __forceinline__ void gload16(const void* g, void* l) {
    __builtin_amdgcn_global_load_lds(
        (const __attribute__((address_space(1))) void*)g,
        (__attribute__((address_space(3))) void*)l, 16, 0, 0);
}

// ---------------------------------------------------------------------------
// K0a: convert weights to bf16.  grid 1024, block 256.
// ---------------------------------------------------------------------------
__global__ __launch_bounds__(256) void convert_w(
    const float* __restrict__ Wq, const float* __restrict__ Wkv,
    const float* __restrict__ Wp,
    bf16* __restrict__ Wqkv_bf, bf16* __restrict__ Wp_bf)
{
    int row = blockIdx.x, tid = threadIdx.x;
    const float* src; bf16* dst;
    if (row < 768) {
        src = (row < 256) ? Wq + (size_t)row * 256 : Wkv + (size_t)(row - 256) * 256;
        dst = Wqkv_bf + (size_t)row * 256;
    } else {
        src = Wp + (size_t)(row - 768) * 256;
        dst = Wp_bf + (size_t)(row - 768) * 256;
    }
    *reinterpret_cast<unsigned short*>(dst + tid) = f2bf(src[tid]);
}

// ---------------------------------------------------------------------------
// K0b: xT[b][pos][c] = bf16(x[b][c][pos]).  64x64 LDS tile transpose.
// grid (64, 4, 16), block 256.
// ---------------------------------------------------------------------------
__global__ __launch_bounds__(256) void x_to_bf16T(
    const float* __restrict__ x, bf16* __restrict__ xT)
{
    __shared__ float t[64][65];
    const int b = blockIdx.z, pos0 = blockIdx.x * 64, c0 = blockIdx.y * 64;
    const int tid = threadIdx.x;
    const int cc = tid >> 6, p = tid & 63;
    #pragma unroll
    for (int i = 0; i < 16; ++i)
        t[cc + 4 * i][p] = x[((size_t)(b * 256 + c0 + cc + 4 * i)) * 4096 + pos0 + p];
    __syncthreads();
    const int pl = tid >> 2, qd = tid & 3;
    unsigned short tmp[16];
    #pragma unroll
    for (int j = 0; j < 16; ++j) tmp[j] = f2bf(t[qd * 16 + j][pl]);
    uint4* dst = reinterpret_cast<uint4*>(xT + ((size_t)(b * 4096 + pos0 + pl)) * 256 + c0 + qd * 16);
    dst[0] = reinterpret_cast<const uint4*>(tmp)[0];
    dst[1] = reinterpret_cast<const uint4*>(tmp)[1];
}

// ---------------------------------------------------------------------------
// K1: qkv MFMA GEMM.  D[m=pos][n=ch] = xT[b] (4096x256) . Wqkv^T (256x768).
// 128x128 tile, BK=32, 4 waves x (4x4 16x16x32 mfma).  grid (512, 6), block 256.
// ---------------------------------------------------------------------------
__global__ __launch_bounds__(256) void qkv_mfma(
    const bf16* __restrict__ xT, const bf16* __restrict__ Wqkv,
    bf16* __restrict__ q, bf16* __restrict__ k, bf16* __restrict__ v)
{
    __shared__ __align__(16) short As[128 * 32];
    __shared__ __align__(16) short Bs[128 * 32];
    const int b = blockIdx.x >> 5;
    const int m0 = (blockIdx.x & 31) * 128;
    const int j0 = blockIdx.y * 128;
    const int tid = threadIdx.x;
    const int w = tid >> 6, lane = tid & 63;
    const int wm = w & 1, wn = w >> 1;
    const int quad = lane >> 4, ln = lane & 15;

    const short* Ag = (const short*)xT + ((size_t)(b * 4096 + m0)) * 256;
    const short* Bg = (const short*)Wqkv + (size_t)j0 * 256;
    const int ldrow = lane >> 2;            // 0..15
    const int ldcol = (lane & 3) * 8;       // element offset within row

    f32x4 acc[4][4] = {};

    for (int k0 = 0; k0 < 256; k0 += 32) {
        __syncthreads();
        #pragma unroll
        for (int p = 0; p < 2; ++p) {
            int row = w * 32 + p * 16;
            gload16(Ag + (size_t)(row + ldrow) * 256 + k0 + ldcol, As + row * 32);
            gload16(Bg + (size_t)(row + ldrow) * 256 + k0 + ldcol, Bs + row * 32);
        }
        __syncthreads();
        short8 af[4], bfr[4];
        #pragma unroll
        for (int mi = 0; mi < 4; ++mi)
            af[mi] = *reinterpret_cast<const short8*>(&As[(wm * 64 + mi * 16 + ln) * 32 + quad * 8]);
        #pragma unroll
        for (int ni = 0; ni < 4; ++ni)
            bfr[ni] = *reinterpret_cast<const short8*>(&Bs[(wn * 64 + ni * 16 + ln) * 32 + quad * 8]);
        #pragma unroll
        for (int mi = 0; mi < 4; ++mi)
            #pragma unroll
            for (int ni = 0; ni < 4; ++ni)
                acc[mi][ni] = __builtin_amdgcn_mfma_f32_16x16x32_bf16(
                    af[mi], bfr[ni], acc[mi][ni], 0, 0, 0);
    }

    bf16* dst; int cb;
    if (j0 < 256)      { dst = q; cb = j0; }
    else if (j0 < 512) { dst = k; cb = j0 - 256; }
    else               { dst = v; cb = j0 - 512; }
    #pragma unroll
    for (int mi = 0; mi < 4; ++mi)
        #pragma unroll
        for (int r = 0; r < 4; ++r) {
            int pos = m0 + wm * 64 + mi * 16 + quad * 4 + r;
            unsigned short* o = reinterpret_cast<unsigned short*>(
                dst + ((size_t)(b * 4096 + pos)) * 256 + cb + wn * 64 + ln);
            #pragma unroll
            for (int ni = 0; ni < 4; ++ni)
                o[ni * 16] = f2bf(acc[mi][ni][r]);
        }
}

// ---------------------------------------------------------------------------
// K2: agent tokens = adaptive avg pool 64x64 -> 7x7 of q.  grid 784, block 256.
// ---------------------------------------------------------------------------
__global__ __launch_bounds__(256) void pool_agent(
    const bf16* __restrict__ q, float* __restrict__ agent)
{
    int bid = blockIdx.x;
    int b = bid / 49, a = bid % 49;
    int py = a / 7, px = a % 7;
    int ys = (py * 64) / 7, ye = ((py + 1) * 64 + 6) / 7;
    int xs = (px * 64) / 7, xe = ((px + 1) * 64 + 6) / 7;
    int ch = threadIdx.x;
    float s = 0.f;
    for (int y = ys; y < ye; ++y)
        for (int x = xs; x < xe; ++x)
            s += bf2f(q[((size_t)(b * 4096) + y * 64 + x) * 256 + ch]);
    agent[((size_t)(b * 49) + a) * 256 + ch] = s / (float)((ye - ys) * (xe - xs));
}

// ---------------------------------------------------------------------------
// K3a: pbias[h][a][pos] (bilerp + ah + aw).  grid 392, block 256.
// ---------------------------------------------------------------------------
__global__ __launch_bounds__(256) void make_pbias(
    const float* __restrict__ an, const float* __restrict__ ahb,
    const float* __restrict__ awb, float* __restrict__ pbias)
{
    int bid = blockIdx.x;               // h*49 + a
    __shared__ float bb[49], ay[64], ax[64];
    int tid = threadIdx.x;
    if (tid < 49) bb[tid] = an[(size_t)bid * 49 + tid];
    if (tid < 64) {
        ay[tid] = ahb[(size_t)bid * 64 + tid];
        ax[tid] = awb[(size_t)bid * 64 + tid];
    }
    __syncthreads();
    for (int it = 0; it < 16; ++it) {
        int pos = it * 256 + tid;
        int y = pos >> 6, x = pos & 63;
        float fy = (y + 0.5f) * (7.f / 64.f) - 0.5f; fy = fminf(fmaxf(fy, 0.f), 6.f);
        float fx = (x + 0.5f) * (7.f / 64.f) - 0.5f; fx = fminf(fmaxf(fx, 0.f), 6.f);
        int y0 = (int)fy, x0 = (int)fx;
        int y1 = min(y0 + 1, 6), x1 = min(x0 + 1, 6);
        float wy = fy - y0, wx = fx - x0;
        float val = (1.f - wy) * ((1.f - wx) * bb[y0 * 7 + x0] + wx * bb[y0 * 7 + x1])
                  + wy * ((1.f - wx) * bb[y1 * 7 + x0] + wx * bb[y1 * 7 + x1]);
        pbias[(size_t)bid * 4096 + pos] = val + ay[y] + ax[x];
    }
}

// ---------------------------------------------------------------------------
// K3b: ab2[h][pos][64] bf16 (bilerp + ha + wa), pos-major with a padded to 64
// so stage2's MFMA D-layout (col=a=ln) gets 64B-segment bias loads.
// grid (8, 16), block 256 (one thread per pos).
// ---------------------------------------------------------------------------
__global__ __launch_bounds__(256) void make_abias2(
    const float* __restrict__ na, const float* __restrict__ hab,
    const float* __restrict__ wab, bf16* __restrict__ ab2)
{
    const int h = blockIdx.x, p0 = blockIdx.y * 256;
    const int tid = threadIdx.x;
    __shared__ float bb[49 * 49];     // na[h][a][grid]
    __shared__ float hy[64 * 49];     // ha[h][y][a]
    __shared__ float wxs[64 * 49];    // wa[h][x][a]
    for (int i = tid; i < 49 * 49; i += 256) bb[i] = na[(size_t)h * 2401 + i];
    for (int i = tid; i < 64 * 49; i += 256) {
        hy[i]  = hab[(size_t)h * 3136 + i];
        wxs[i] = wab[(size_t)h * 3136 + i];
    }
    __syncthreads();
    const int pos = p0 + tid;
    const int y = pos >> 6, x = pos & 63;
    float fy = (y + 0.5f) * (7.f / 64.f) - 0.5f; fy = fminf(fmaxf(fy, 0.f), 6.f);
    float fx = (x + 0.5f) * (7.f / 64.f) - 0.5f; fx = fminf(fmaxf(fx, 0.f), 6.f);
    int y0 = (int)fy, x0 = (int)fx;
    int y1 = min(y0 + 1, 6), x1 = min(x0 + 1, 6);
    float wy = fy - y0, wxv = fx - x0;
    float w00 = (1.f - wy) * (1.f - wxv), w01 = (1.f - wy) * wxv;
    float w10 = wy * (1.f - wxv),        w11 = wy * wxv;
    int g00 = y0 * 7 + x0, g01 = y0 * 7 + x1, g10 = y1 * 7 + x0, g11 = y1 * 7 + x1;
    unsigned short outv[64];
    #pragma unroll
    for (int a = 0; a < 49; ++a) {
        float val = w00 * bb[a * 49 + g00] + w01 * bb[a * 49 + g01]
                  + w10 * bb[a * 49 + g10] + w11 * bb[a * 49 + g11]
                  + hy[y * 49 + a] + wxs[x * 49 + a];
        outv[a] = f2bf(val);
    }
    #pragma unroll
    for (int a = 49; a < 64; ++a) outv[a] = 0;
    uint4* dst = reinterpret_cast<uint4*>(
        reinterpret_cast<unsigned short*>(ab2) + ((size_t)(h * 4096) + pos) * 64);
    #pragma unroll
    for (int j = 0; j < 8; ++j) dst[j] = reinterpret_cast<const uint4*>(outv)[j];
}

// ---------------------------------------------------------------------------
// K4: stage-1 attention via MFMA (linear softmax, split over n).
// grid 1024 (=16*8*8 splits of 512), block 256 (4 waves).
// ---------------------------------------------------------------------------
__global__ __launch_bounds__(256) void stage1(
    const float* __restrict__ agent, const bf16* __restrict__ k,
    const bf16* __restrict__ v, const float* __restrict__ pbias,
    float* __restrict__ part_O, float* __restrict__ part_sum)
{
    const int bid = blockIdx.x;
    const int split = bid & 7, h = (bid >> 3) & 7, b = bid >> 6;
    const int tid = threadIdx.x;
    const int w = tid >> 6, lane = tid & 63;
    const int ln = lane & 15, quad = lane >> 4;

    __shared__ __align__(16) short agLds[64 * 32];    // [a][d] bf16
    __shared__ __align__(16) short pLds[64 * 140];    // [a][n_loc] bf16, pad->140
    __shared__ __align__(16) short vtLds[32 * 140];   // [d][n_loc] bf16

    // stage agents once: rows >= 49 zeroed
    for (int i = tid; i < 64 * 32; i += 256) {
        int a = i >> 5, d = i & 31;
        float val = (a < 49) ? agent[((size_t)(b * 49) + a) * 256 + h * 32 + d] : 0.f;
        agLds[i] = (short)f2bf(val);
    }
    __syncthreads();

    const short8 agFrag = *reinterpret_cast<const short8*>(&agLds[(w * 16 + ln) * 32 + quad * 8]);
    const int a_row = w * 16 + quad * 4;    // + r gives agent index

    f32x4 oAcc[2] = {};
    float sacc[4] = {0.f, 0.f, 0.f, 0.f};
    const f32x4 zero4 = {0.f, 0.f, 0.f, 0.f};

    for (int sub = 0; sub < 4; ++sub) {
        const int nbase = split * 512 + sub * 128;
        __syncthreads();     // pLds/vtLds free from previous sub's PV
        // ---- vT staging: thread t -> n_loc = t&127, d-half = (t>>7)*16
        {
            const int n_loc = tid & 127, dh = (tid >> 7) * 16;
            const short* vr = (const short*)v + ((size_t)(b * 4096) + nbase + n_loc) * 256 + h * 32 + dh;
            uint4 u0 = *reinterpret_cast<const uint4*>(vr);
            uint4 u1 = *reinterpret_cast<const uint4*>(vr + 8);
            unsigned int uu[8] = {u0.x, u0.y, u0.z, u0.w, u1.x, u1.y, u1.z, u1.w};
            #pragma unroll
            for (int j = 0; j < 8; ++j) {
                vtLds[(dh + 2 * j) * 140 + n_loc]     = (short)(uu[j] & 0xffffu);
                vtLds[(dh + 2 * j + 1) * 140 + n_loc] = (short)(uu[j] >> 16);
            }
        }
        // ---- score: wave w computes S rows [w*16,w*16+16) x 128 cols
        short8 kf[8];
        #pragma unroll
        for (int t = 0; t < 8; ++t) {
            int n = nbase + t * 16 + ln;
            kf[t] = *reinterpret_cast<const short8*>(
                (const short*)k + ((size_t)(b * 4096) + n) * 256 + h * 32 + quad * 8);
        }
        #pragma unroll
        for (int t = 0; t < 8; ++t) {
            f32x4 s = __builtin_amdgcn_mfma_f32_16x16x32_bf16(agFrag, kf[t], zero4, 0, 0, 0);
            int n = nbase + t * 16 + ln;
            #pragma unroll
            for (int r = 0; r < 4; ++r) {
                int a = a_row + r;
                float e = 0.f;
                if (a < 49) {
                    float sv = s[r] * SCALE + pbias[((size_t)(h * 49) + a) * 4096 + n];
                    e = __expf(sv);
                }
                sacc[r] += e;
                pLds[(a_row + r) * 140 + t * 16 + ln] = (short)f2bf(e);
            }
        }
        __syncthreads();     // pLds + vtLds ready
        // ---- PV: O[m=a][d] += P . V, K = 128 (4 mfma k-steps)
        #pragma unroll
        for (int ks = 0; ks < 4; ++ks) {
            short8 pf = *reinterpret_cast<const short8*>(&pLds[(w * 16 + ln) * 140 + ks * 32 + quad * 8]);
            #pragma unroll
            for (int dt = 0; dt < 2; ++dt) {
                short8 vf = *reinterpret_cast<const short8*>(&vtLds[(dt * 16 + ln) * 140 + ks * 32 + quad * 8]);
                oAcc[dt] = __builtin_amdgcn_mfma_f32_16x16x32_bf16(pf, vf, oAcc[dt], 0, 0, 0);
            }
        }
    }

    // ---- write partials
    const size_t obase = ((size_t)((b * 8 + h) * 8 + split)) * 1568;
    #pragma unroll
    for (int dt = 0; dt < 2; ++dt)
        #pragma unroll
        for (int r = 0; r < 4; ++r) {
            int a = a_row + r;
            if (a < 49)
                part_O[obase + a * 32 + dt * 16 + ln] = oAcc[dt][r];
        }
    #pragma unroll
    for (int r = 0; r < 4; ++r) {
        float sv = sacc[r];
        #pragma unroll
        for (int m = 1; m < 16; m <<= 1) sv += __shfl_xor(sv, m, 64);
        if (ln == 0) {
            int a = a_row + r;
            if (a < 49)
                part_sum[((b * 8 + h) * 8 + split) * 49 + a] = sv;
        }
    }
}

// K4b: combine split partials -> avT[bh][d][64] bf16 (zero-padded a>=49),
// which is exactly stage2's PV B-fragment layout.  grid 128, block 256.
__global__ __launch_bounds__(256) void stage1_fin(
    const float* __restrict__ part_O, const float* __restrict__ part_sum,
    bf16* __restrict__ avT)
{
    int bh = blockIdx.x;
    __shared__ float inv[49];
    int tid = threadIdx.x;
    if (tid < 49) {
        float s = 0.f;
        #pragma unroll
        for (int sp = 0; sp < 8; ++sp) s += part_sum[(bh * 8 + sp) * 49 + tid];
        inv[tid] = 1.f / s;
    }
    __syncthreads();
    unsigned short* dst = reinterpret_cast<unsigned short*>(avT) + (size_t)bh * 2048;
    for (int i = tid; i < 2048; i += 256) {
        int d = i >> 6, a = i & 63;
        float val = 0.f;
        if (a < 49) {
            float o = 0.f;
            #pragma unroll
            for (int sp = 0; sp < 8; ++sp)
                o += part_O[((size_t)(bh * 8) + sp) * 1568 + a * 32 + d];
            val = o * inv[a];
        }
        dst[i] = f2bf(val);
    }
}

// ---------------------------------------------------------------------------
// K5: stage-2 attention via MFMA + fused depthwise conv.
// Per (b,h): S[pos][a] = q.agent^T (4 mfma, a padded to 64) -> bias+exp ->
// row-softmax via shfl_xor over 16-lane D-column groups -> normalized P (bf16)
// through LDS into A-fragment layout -> O = P.avT^T (4 mfma, K=64) ->
// O transposed through LDS so each thread owns one pos x 8 ch for the
// vectorized dwconv + 16B mid store.
// grid (128, 16), block 256 (4 waves x 16 pos x 4 subs = 256 pos/block).
// ---------------------------------------------------------------------------
__global__ __launch_bounds__(256) void stage2_mfma(
    const bf16* __restrict__ q, const bf16* __restrict__ v,
    const float* __restrict__ agent, const bf16* __restrict__ avT,
    const bf16* __restrict__ ab2, const float* __restrict__ wdwc,
    const float* __restrict__ bdwc, bf16* __restrict__ mid)
{
    const int bh = blockIdx.x;
    const int b = bh >> 3, h = bh & 7;
    const int base = blockIdx.y * 256;
    const int tid = threadIdx.x;
    const int w = tid >> 6, lane = tid & 63;
    const int quad = lane >> 4, ln = lane & 15;

    __shared__ __align__(16) short agLds[64 * 32];      // [a][d] bf16, a>=49 zero
    __shared__ __align__(16) short pLds[4][16 * 72];    // per-wave P, row=pos_loc
    __shared__ __align__(16) float oLds[64 * 36];       // O transpose buffer
    __shared__ float wdLds[32 * 9];
    __shared__ float bdLds[32];

    // stage agents (bf16) + dwconv weights
    for (int i = tid; i < 64 * 32; i += 256) {
        int a = i >> 5, d = i & 31;
        float val = (a < 49) ? agent[((size_t)(b * 49) + a) * 256 + h * 32 + d] : 0.f;
        agLds[i] = (short)f2bf(val);
    }
    for (int i = tid; i < 288; i += 256) wdLds[i] = wdwc[(size_t)(h * 32) * 9 + i];
    if (tid < 32) bdLds[tid] = bdwc[h * 32 + tid];
    __syncthreads();

    // agent B-fragments (rows = a), hoisted
    short8 agF[4];
    #pragma unroll
    for (int t = 0; t < 4; ++t)
        agF[t] = *reinterpret_cast<const short8*>(&agLds[(t * 16 + ln) * 32 + quad * 8]);

    // agent_v B-fragments (rows = d, k over a), hoisted (sub-independent)
    short8 avF[2][2];
    #pragma unroll
    for (int dt = 0; dt < 2; ++dt)
        #pragma unroll
        for (int kc = 0; kc < 2; ++kc)
            avF[dt][kc] = *reinterpret_cast<const short8*>(
                (const short*)avT + ((size_t)bh * 32 + dt * 16 + ln) * 64 + kc * 32 + quad * 8);

    const int prow = tid >> 2, cl = (tid & 3) * 8;   // dwconv mapping
    const f32x4 zero4 = {0.f, 0.f, 0.f, 0.f};

    for (int sub = 0; sub < 4; ++sub) {
        const int pos0w = base + sub * 64 + w * 16;
        // ---- S = q . agent^T  (A rows = pos, one K=32 step)
        short8 qf = *reinterpret_cast<const short8*>(
            (const short*)q + ((size_t)(b * 4096) + pos0w + ln) * 256 + h * 32 + quad * 8);
        f32x4 sT[4];
        #pragma unroll
        for (int t = 0; t < 4; ++t)
            sT[t] = __builtin_amdgcn_mfma_f32_16x16x32_bf16(qf, agF[t], zero4, 0, 0, 0);
        // ---- bias + exp + masked row-sum
        float e[4][4];
        float part[4] = {0.f, 0.f, 0.f, 0.f};
        #pragma unroll
        for (int t = 0; t < 4; ++t) {
            int a = t * 16 + ln;
            #pragma unroll
            for (int r = 0; r < 4; ++r) {
                float ev = 0.f;
                if (a < 49) {
                    int pos = pos0w + quad * 4 + r;
                    float bias = bf2f(ab2[((size_t)(h * 4096) + pos) * 64 + a]);
                    ev = __expf(sT[t][r] * SCALE + bias);
                }
                e[t][r] = ev;
                part[r] += ev;
            }
        }
        #pragma unroll
        for (int r = 0; r < 4; ++r) {
            #pragma unroll
            for (int m = 1; m < 16; m <<= 1) part[r] += __shfl_xor(part[r], m, 64);
            part[r] = 1.f / part[r];
        }
        // ---- normalized P -> LDS in A-fragment layout (row = pos_loc)
        #pragma unroll
        for (int t = 0; t < 4; ++t)
            #pragma unroll
            for (int r = 0; r < 4; ++r)
                pLds[w][(quad * 4 + r) * 72 + t * 16 + ln] = (short)f2bf(e[t][r] * part[r]);
        __syncthreads();   // P visible; also: previous sub's oLds readers done
        // ---- O = P . avT^T  (K = 64 over padded a)
        f32x4 oAcc[2] = {};
        #pragma unroll
        for (int kc = 0; kc < 2; ++kc) {
            short8 pf = *reinterpret_cast<const short8*>(&pLds[w][ln * 72 + kc * 32 + quad * 8]);
            #pragma unroll
            for (int dt = 0; dt < 2; ++dt)
                oAcc[dt] = __builtin_amdgcn_mfma_f32_16x16x32_bf16(pf, avF[dt][kc], oAcc[dt], 0, 0, 0);
        }
        // ---- transpose O through LDS (row = sub-local pos, col = ch_loc)
        #pragma unroll
        for (int dt = 0; dt < 2; ++dt)
            #pragma unroll
            for (int r = 0; r < 4; ++r)
                oLds[(w * 16 + quad * 4 + r) * 36 + dt * 16 + ln] = oAcc[dt][r];
        __syncthreads();
        // ---- dwconv + mid write: thread owns pos = base+sub*64+prow, 8 ch at cl
        {
            int pos = base + sub * 64 + prow;
            float acc[8];
            #pragma unroll
            for (int j = 0; j < 8; ++j) acc[j] = oLds[prow * 36 + cl + j] + bdLds[cl + j];
            int y = pos >> 6, x = pos & 63;
            #pragma unroll
            for (int dy = -1; dy <= 1; ++dy) {
                int yy = y + dy; if (yy < 0 || yy > 63) continue;
                #pragma unroll
                for (int dx = -1; dx <= 1; ++dx) {
                    int xx = x + dx; if (xx < 0 || xx > 63) continue;
                    int widx = (dy + 1) * 3 + (dx + 1);
                    const bf16* vr = v + ((size_t)(b * 4096) + yy * 64 + xx) * 256 + h * 32 + cl;
                    float f[8]; load8bf(vr, f);
                    #pragma unroll
                    for (int j = 0; j < 8; ++j)
                        acc[j] = fmaf(wdLds[(cl + j) * 9 + widx], f[j], acc[j]);
                }
            }
            unsigned short o16[8];
            #pragma unroll
            for (int j = 0; j < 8; ++j) o16[j] = f2bf(acc[j]);
            *reinterpret_cast<uint4*>(mid + ((size_t)(b * 4096) + pos) * 256 + h * 32 + cl) =
                *reinterpret_cast<const uint4*>(o16);
        }
        // next sub: pLds is wave-private (safe); oLds protected by the barrier
        // after the next sub's P write.
    }
}

// ---------------------------------------------------------------------------
// K7: proj MFMA GEMM.  D[m=ch][n=pos] = Wp (256x256) . mid[b]^T (256x4096).
// grid (2, 512), block 256.
// ---------------------------------------------------------------------------
__global__ __launch_bounds__(256) void proj_mfma(
    const bf16* __restrict__ mid, const bf16* __restrict__ Wp,
    const float* __restrict__ bp, float* __restrict__ out)
{
    __shared__ __align__(16) short As[128 * 32];
    __shared__ __align__(16) short Bs[128 * 32];
    const int m0 = blockIdx.x * 128;           // ch tile
    const int b  = blockIdx.y >> 5;
    const int n0 = (blockIdx.y & 31) * 128;    // pos tile
    const int tid = threadIdx.x;
    const int w = tid >> 6, lane = tid & 63;
    const int wm = w & 1, wn = w >> 1;
    const int quad = lane >> 4, ln = lane & 15;

    const short* Ag = (const short*)Wp + (size_t)m0 * 256;
    const short* Bg = (const short*)mid + ((size_t)(b * 4096 + n0)) * 256;
    const int ldrow = lane >> 2;
    const int ldcol = (lane & 3) * 8;

    f32x4 acc[4][4] = {};

    for (int k0 = 0; k0 < 256; k0 += 32) {
        __syncthreads();
        #pragma unroll
        for (int p = 0; p < 2; ++p) {
            int row = w * 32 + p * 16;
            gload16(Ag + (size_t)(row + ldrow) * 256 + k0 + ldcol, As + row * 32);
            gload16(Bg + (size_t)(row + ldrow) * 256 + k0 + ldcol, Bs + row * 32);
        }
        __syncthreads();
        short8 af[4], bfr[4];
        #pragma unroll
        for (int mi = 0; mi < 4; ++mi)
            af[mi] = *reinterpret_cast<const short8*>(&As[(wm * 64 + mi * 16 + ln) * 32 + quad * 8]);
        #pragma unroll
        for (int ni = 0; ni < 4; ++ni)
            bfr[ni] = *reinterpret_cast<const short8*>(&Bs[(wn * 64 + ni * 16 + ln) * 32 + quad * 8]);
        #pragma unroll
        for (int mi = 0; mi < 4; ++mi)
            #pragma unroll
            for (int ni = 0; ni < 4; ++ni)
                acc[mi][ni] = __builtin_amdgcn_mfma_f32_16x16x32_bf16(
                    af[mi], bfr[ni], acc[mi][ni], 0, 0, 0);
    }

    #pragma unroll
    for (int mi = 0; mi < 4; ++mi)
        #pragma unroll
        for (int r = 0; r < 4; ++r) {
            int ch = m0 + wm * 64 + mi * 16 + quad * 4 + r;
            float bias = bp[ch];
            float* o = out + ((size_t)(b * 256 + ch)) * 4096 + n0 + wn * 64 + ln;
            #pragma unroll
            for (int ni = 0; ni < 4; ++ni)
                o[ni * 16] = acc[mi][ni][r] + bias;
        }
}

extern "C" void kernel_launch(void* const* d_in, const int* in_sizes, int n_in,
                              void* d_out, int out_size, void* d_ws, size_t ws_size,
                              hipStream_t stream)
{
    const float* x       = (const float*)d_in[0];
    const float* Wq      = (const float*)d_in[1];
    const float* Wkv     = (const float*)d_in[2];
    const float* Wproj   = (const float*)d_in[3];
    const float* bproj   = (const float*)d_in[4];
    const float* Wdwc    = (const float*)d_in[5];
    const float* bdwc    = (const float*)d_in[6];
    const float* an_bias = (const float*)d_in[7];
    const float* na_bias = (const float*)d_in[8];
    const float* ah_bias = (const float*)d_in[9];
    const float* aw_bias = (const float*)d_in[10];
    const float* ha_bias = (const float*)d_in[11];
    const float* wa_bias = (const float*)d_in[12];
    // H=64, W=64 hard-coded (d_in[13], d_in[14])

    char* ws = (char*)d_ws;
    bf16*  q      = (bf16*)(ws + 0);
    bf16*  k      = (bf16*)(ws + 33554432);
    bf16*  v      = (bf16*)(ws + 67108864);
    // the 33.5 MB region at 100663296 is triple-used over time:
    //   1) xT (qkv input), 2) stage1 partials, 3) mid (stage2 out / proj in)
    bf16*  xT     = (bf16*)(ws + 100663296);
    float* part_O   = (float*)(ws + 100663296);
    float* part_sum = (float*)(ws + 100663296 + 6422528);
    bf16*  mid    = (bf16*)(ws + 100663296);
    float* agent  = (float*)(ws + 134217728);
    bf16*  avT    = (bf16*)(ws + 135020544);   // [bh][d][64] bf16, 512 KB
    float* pbias  = (float*)(ws + 135823360);
    bf16*  ab2    = (bf16*)(ws + 142245888);   // [h][pos][64] bf16, 4 MB
    bf16*  Wqkv_bf = (bf16*)(ws + 148668416);
    bf16*  Wp_bf   = (bf16*)(ws + 149061632);
    float* out    = (float*)d_out;

    convert_w  <<<dim3(1024),      256, 0, stream>>>(Wq, Wkv, Wproj, Wqkv_bf, Wp_bf);
    x_to_bf16T <<<dim3(64, 4, 16), 256, 0, stream>>>(x, xT);
    qkv_mfma   <<<dim3(512, 6),    256, 0, stream>>>(xT, Wqkv_bf, q, k, v);
    pool_agent <<<dim3(784),       256, 0, stream>>>(q, agent);
    make_pbias <<<dim3(392),       256, 0, stream>>>(an_bias, ah_bias, aw_bias, pbias);
    make_abias2<<<dim3(8, 16),     256, 0, stream>>>(na_bias, ha_bias, wa_bias, ab2);
    stage1     <<<dim3(1024),      256, 0, stream>>>(agent, k, v, pbias, part_O, part_sum);
    stage1_fin <<<dim3(128),       256, 0, stream>>>(part_O, part_sum, avT);
    stage2_mfma<<<dim3(128, 16),   256, 0, stream>>>(q, v, agent, avT, ab2, Wdwc, bdwc, mid);
    proj_mfma  <<<dim3(2, 512),    256, 0, stream>>>(mid, Wp_bf, bproj, out);
}

// Round 2
// 371.768 us; speedup vs baseline: 1.0417x; 1.0417x over previous
//
#include <hip/hip_runtime.h>
#include <hip/hip_bf16.h>
#include <stdint.h>

using bf16 = __hip_bfloat16;

#define SCALE 0.17677669529663687f   // 32^-0.5

typedef short short8 __attribute__((ext_vector_type(8)));
typedef float f32x4 __attribute__((ext_vector_type(4)));

__device__ __forceinline__ float bf2f(bf16 v) { return __bfloat162float(v); }

__device__ __forceinline__ unsigned short f2bf(float f) {
    unsigned int u = __float_as_uint(f);
    unsigned int r = u + 0x7fffu + ((u >> 16) & 1u);   // RNE; inputs never NaN/Inf
    return (unsigned short)(r >> 16);
}

// load 8 consecutive bf16 (16B-aligned) -> 8 floats
__device__ __forceinline__ void load8bf(const bf16* p, float* f) {
    uint4 u = *reinterpret_cast<const uint4*>(p);
    f[0] = __uint_as_float(u.x << 16); f[1] = __uint_as_float(u.x & 0xffff0000u);
    f[2] = __uint_as_float(u.y << 16); f[3] = __uint_as_float(u.y & 0xffff0000u);
    f[4] = __uint_as_float(u.z << 16); f[5] = __uint_as_float(u.z & 0xffff0000u);
    f[6] = __uint_as_float(u.w << 16); f[7] = __uint_as_float(u.w & 0xffff0000u);
}

__device__ __forceinline__ void gload16(const void* g, void* l) {
    __builtin_amdgcn_global_load_lds(
        (const __attribute__((address_space(1))) void*)g,
        (__attribute__((address_space(3))) void*)l, 16, 0, 0);
}

// ---------------------------------------------------------------------------
// K0a: convert weights to bf16.  grid 1024, block 256.
// ---------------------------------------------------------------------------
__global__ __launch_bounds__(256) void convert_w(
    const float* __restrict__ Wq, const float* __restrict__ Wkv,
    const float* __restrict__ Wp,
    bf16* __restrict__ Wqkv_bf, bf16* __restrict__ Wp_bf)
{
    int row = blockIdx.x, tid = threadIdx.x;
    const float* src; bf16* dst;
    if (row < 768) {
        src = (row < 256) ? Wq + (size_t)row * 256 : Wkv + (size_t)(row - 256) * 256;
        dst = Wqkv_bf + (size_t)row * 256;
    } else {
        src = Wp + (size_t)(row - 768) * 256;
        dst = Wp_bf + (size_t)(row - 768) * 256;
    }
    *reinterpret_cast<unsigned short*>(dst + tid) = f2bf(src[tid]);
}

// ---------------------------------------------------------------------------
// K0b: xT[b][pos][c] = bf16(x[b][c][pos]).  64x64 LDS tile transpose.
// grid (64, 4, 16), block 256.
// ---------------------------------------------------------------------------
__global__ __launch_bounds__(256) void x_to_bf16T(
    const float* __restrict__ x, bf16* __restrict__ xT)
{
    __shared__ float t[64][65];
    const int b = blockIdx.z, pos0 = blockIdx.x * 64, c0 = blockIdx.y * 64;
    const int tid = threadIdx.x;
    const int cc = tid >> 6, p = tid & 63;
    #pragma unroll
    for (int i = 0; i < 16; ++i)
        t[cc + 4 * i][p] = x[((size_t)(b * 256 + c0 + cc + 4 * i)) * 4096 + pos0 + p];
    __syncthreads();
    const int pl = tid >> 2, qd = tid & 3;
    unsigned short tmp[16];
    #pragma unroll
    for (int j = 0; j < 16; ++j) tmp[j] = f2bf(t[qd * 16 + j][pl]);
    uint4* dst = reinterpret_cast<uint4*>(xT + ((size_t)(b * 4096 + pos0 + pl)) * 256 + c0 + qd * 16);
    dst[0] = reinterpret_cast<const uint4*>(tmp)[0];
    dst[1] = reinterpret_cast<const uint4*>(tmp)[1];
}

// ---------------------------------------------------------------------------
// K1: qkv MFMA GEMM.  D[m=pos][n=ch] = xT[b] (4096x256) . Wqkv^T (256x768).
// 128x128 tile, BK=32, 4 waves x (4x4 16x16x32 mfma).  grid (512, 6), block 256.
// ---------------------------------------------------------------------------
__global__ __launch_bounds__(256) void qkv_mfma(
    const bf16* __restrict__ xT, const bf16* __restrict__ Wqkv,
    bf16* __restrict__ q, bf16* __restrict__ k, bf16* __restrict__ v)
{
    __shared__ __align__(16) short As[128 * 32];
    __shared__ __align__(16) short Bs[128 * 32];
    const int b = blockIdx.x >> 5;
    const int m0 = (blockIdx.x & 31) * 128;
    const int j0 = blockIdx.y * 128;
    const int tid = threadIdx.x;
    const int w = tid >> 6, lane = tid & 63;
    const int wm = w & 1, wn = w >> 1;
    const int quad = lane >> 4, ln = lane & 15;

    const short* Ag = (const short*)xT + ((size_t)(b * 4096 + m0)) * 256;
    const short* Bg = (const short*)Wqkv + (size_t)j0 * 256;
    const int ldrow = lane >> 2;            // 0..15
    const int ldcol = (lane & 3) * 8;       // element offset within row

    f32x4 acc[4][4] = {};

    for (int k0 = 0; k0 < 256; k0 += 32) {
        __syncthreads();
        #pragma unroll
        for (int p = 0; p < 2; ++p) {
            int row = w * 32 + p * 16;
            gload16(Ag + (size_t)(row + ldrow) * 256 + k0 + ldcol, As + row * 32);
            gload16(Bg + (size_t)(row + ldrow) * 256 + k0 + ldcol, Bs + row * 32);
        }
        __syncthreads();
        short8 af[4], bfr[4];
        #pragma unroll
        for (int mi = 0; mi < 4; ++mi)
            af[mi] = *reinterpret_cast<const short8*>(&As[(wm * 64 + mi * 16 + ln) * 32 + quad * 8]);
        #pragma unroll
        for (int ni = 0; ni < 4; ++ni)
            bfr[ni] = *reinterpret_cast<const short8*>(&Bs[(wn * 64 + ni * 16 + ln) * 32 + quad * 8]);
        #pragma unroll
        for (int mi = 0; mi < 4; ++mi)
            #pragma unroll
            for (int ni = 0; ni < 4; ++ni)
                acc[mi][ni] = __builtin_amdgcn_mfma_f32_16x16x32_bf16(
                    af[mi], bfr[ni], acc[mi][ni], 0, 0, 0);
    }

    bf16* dst; int cb;
    if (j0 < 256)      { dst = q; cb = j0; }
    else if (j0 < 512) { dst = k; cb = j0 - 256; }
    else               { dst = v; cb = j0 - 512; }
    #pragma unroll
    for (int mi = 0; mi < 4; ++mi)
        #pragma unroll
        for (int r = 0; r < 4; ++r) {
            int pos = m0 + wm * 64 + mi * 16 + quad * 4 + r;
            unsigned short* o = reinterpret_cast<unsigned short*>(
                dst + ((size_t)(b * 4096 + pos)) * 256 + cb + wn * 64 + ln);
            #pragma unroll
            for (int ni = 0; ni < 4; ++ni)
                o[ni * 16] = f2bf(acc[mi][ni][r]);
        }
}

// ---------------------------------------------------------------------------
// K2: agent tokens = adaptive avg pool 64x64 -> 7x7 of q.  grid 784, block 256.
// ---------------------------------------------------------------------------
__global__ __launch_bounds__(256) void pool_agent(
    const bf16* __restrict__ q, float* __restrict__ agent)
{
    int bid = blockIdx.x;
    int b = bid / 49, a = bid % 49;
    int py = a / 7, px = a % 7;
    int ys = (py * 64) / 7, ye = ((py + 1) * 64 + 6) / 7;
    int xs = (px * 64) / 7, xe = ((px + 1) * 64 + 6) / 7;
    int ch = threadIdx.x;
    float s = 0.f;
    for (int y = ys; y < ye; ++y)
        for (int x = xs; x < xe; ++x)
            s += bf2f(q[((size_t)(b * 4096) + y * 64 + x) * 256 + ch]);
    agent[((size_t)(b * 49) + a) * 256 + ch] = s / (float)((ye - ys) * (xe - xs));
}

// ---------------------------------------------------------------------------
// K3a: pbias[h][a][pos] (bilerp + ah + aw).  grid 392, block 256.
// ---------------------------------------------------------------------------
__global__ __launch_bounds__(256) void make_pbias(
    const float* __restrict__ an, const float* __restrict__ ahb,
    const float* __restrict__ awb, float* __restrict__ pbias)
{
    int bid = blockIdx.x;               // h*49 + a
    __shared__ float bb[49], ay[64], ax[64];
    int tid = threadIdx.x;
    if (tid < 49) bb[tid] = an[(size_t)bid * 49 + tid];
    if (tid < 64) {
        ay[tid] = ahb[(size_t)bid * 64 + tid];
        ax[tid] = awb[(size_t)bid * 64 + tid];
    }
    __syncthreads();
    for (int it = 0; it < 16; ++it) {
        int pos = it * 256 + tid;
        int y = pos >> 6, x = pos & 63;
        float fy = (y + 0.5f) * (7.f / 64.f) - 0.5f; fy = fminf(fmaxf(fy, 0.f), 6.f);
        float fx = (x + 0.5f) * (7.f / 64.f) - 0.5f; fx = fminf(fmaxf(fx, 0.f), 6.f);
        int y0 = (int)fy, x0 = (int)fx;
        int y1 = min(y0 + 1, 6), x1 = min(x0 + 1, 6);
        float wy = fy - y0, wx = fx - x0;
        float val = (1.f - wy) * ((1.f - wx) * bb[y0 * 7 + x0] + wx * bb[y0 * 7 + x1])
                  + wy * ((1.f - wx) * bb[y1 * 7 + x0] + wx * bb[y1 * 7 + x1]);
        pbias[(size_t)bid * 4096 + pos] = val + ay[y] + ax[x];
    }
}

// ---------------------------------------------------------------------------
// K3b: ab2[h][pos][j] bf16 (bilerp + ha + wa), pos-major, a padded to 64 and
// PERMUTED j = (a&15)*4 + (a>>4): stage2 lane ln reads its 4 t-values for one
// pos as a single 8B load at j = ln*4.  grid (8, 16), block 256.
// ---------------------------------------------------------------------------
__global__ __launch_bounds__(256) void make_abias2(
    const float* __restrict__ na, const float* __restrict__ hab,
    const float* __restrict__ wab, bf16* __restrict__ ab2)
{
    const int h = blockIdx.x, p0 = blockIdx.y * 256;
    const int tid = threadIdx.x;
    __shared__ float bb[49 * 49];     // na[h][a][grid]
    __shared__ float hy[64 * 49];     // ha[h][y][a]
    __shared__ float wxs[64 * 49];    // wa[h][x][a]
    for (int i = tid; i < 49 * 49; i += 256) bb[i] = na[(size_t)h * 2401 + i];
    for (int i = tid; i < 64 * 49; i += 256) {
        hy[i]  = hab[(size_t)h * 3136 + i];
        wxs[i] = wab[(size_t)h * 3136 + i];
    }
    __syncthreads();
    const int pos = p0 + tid;
    const int y = pos >> 6, x = pos & 63;
    float fy = (y + 0.5f) * (7.f / 64.f) - 0.5f; fy = fminf(fmaxf(fy, 0.f), 6.f);
    float fx = (x + 0.5f) * (7.f / 64.f) - 0.5f; fx = fminf(fmaxf(fx, 0.f), 6.f);
    int y0 = (int)fy, x0 = (int)fx;
    int y1 = min(y0 + 1, 6), x1 = min(x0 + 1, 6);
    float wy = fy - y0, wxv = fx - x0;
    float w00 = (1.f - wy) * (1.f - wxv), w01 = (1.f - wy) * wxv;
    float w10 = wy * (1.f - wxv),        w11 = wy * wxv;
    int g00 = y0 * 7 + x0, g01 = y0 * 7 + x1, g10 = y1 * 7 + x0, g11 = y1 * 7 + x1;
    unsigned short outv[64];
    #pragma unroll
    for (int a = 0; a < 64; ++a) {
        float val = 0.f;
        if (a < 49)
            val = w00 * bb[a * 49 + g00] + w01 * bb[a * 49 + g01]
                + w10 * bb[a * 49 + g10] + w11 * bb[a * 49 + g11]
                + hy[y * 49 + a] + wxs[x * 49 + a];
        outv[(a & 15) * 4 + (a >> 4)] = f2bf(val);
    }
    uint4* dst = reinterpret_cast<uint4*>(
        reinterpret_cast<unsigned short*>(ab2) + ((size_t)(h * 4096) + pos) * 64);
    #pragma unroll
    for (int j = 0; j < 8; ++j) dst[j] = reinterpret_cast<const uint4*>(outv)[j];
}

// ---------------------------------------------------------------------------
// K4: stage-1 attention via MFMA (linear softmax, split over n).
// grid 1024 (=16*8*8 splits of 512), block 256 (4 waves).
// ---------------------------------------------------------------------------
__global__ __launch_bounds__(256) void stage1(
    const float* __restrict__ agent, const bf16* __restrict__ k,
    const bf16* __restrict__ v, const float* __restrict__ pbias,
    float* __restrict__ part_O, float* __restrict__ part_sum)
{
    const int bid = blockIdx.x;
    const int split = bid & 7, h = (bid >> 3) & 7, b = bid >> 6;
    const int tid = threadIdx.x;
    const int w = tid >> 6, lane = tid & 63;
    const int ln = lane & 15, quad = lane >> 4;

    __shared__ __align__(16) short agLds[64 * 32];    // [a][d] bf16
    __shared__ __align__(16) short pLds[64 * 140];    // [a][n_loc] bf16, pad->140
    __shared__ __align__(16) short vtLds[32 * 140];   // [d][n_loc] bf16

    // stage agents once: rows >= 49 zeroed
    for (int i = tid; i < 64 * 32; i += 256) {
        int a = i >> 5, d = i & 31;
        float val = (a < 49) ? agent[((size_t)(b * 49) + a) * 256 + h * 32 + d] : 0.f;
        agLds[i] = (short)f2bf(val);
    }
    __syncthreads();

    const short8 agFrag = *reinterpret_cast<const short8*>(&agLds[(w * 16 + ln) * 32 + quad * 8]);
    const int a_row = w * 16 + quad * 4;    // + r gives agent index

    f32x4 oAcc[2] = {};
    float sacc[4] = {0.f, 0.f, 0.f, 0.f};
    const f32x4 zero4 = {0.f, 0.f, 0.f, 0.f};

    for (int sub = 0; sub < 4; ++sub) {
        const int nbase = split * 512 + sub * 128;
        __syncthreads();     // pLds/vtLds free from previous sub's PV
        // ---- vT staging: thread t -> n_loc = t&127, d-half = (t>>7)*16
        {
            const int n_loc = tid & 127, dh = (tid >> 7) * 16;
            const short* vr = (const short*)v + ((size_t)(b * 4096) + nbase + n_loc) * 256 + h * 32 + dh;
            uint4 u0 = *reinterpret_cast<const uint4*>(vr);
            uint4 u1 = *reinterpret_cast<const uint4*>(vr + 8);
            unsigned int uu[8] = {u0.x, u0.y, u0.z, u0.w, u1.x, u1.y, u1.z, u1.w};
            #pragma unroll
            for (int j = 0; j < 8; ++j) {
                vtLds[(dh + 2 * j) * 140 + n_loc]     = (short)(uu[j] & 0xffffu);
                vtLds[(dh + 2 * j + 1) * 140 + n_loc] = (short)(uu[j] >> 16);
            }
        }
        // ---- score: wave w computes S rows [w*16,w*16+16) x 128 cols
        short8 kf[8];
        #pragma unroll
        for (int t = 0; t < 8; ++t) {
            int n = nbase + t * 16 + ln;
            kf[t] = *reinterpret_cast<const short8*>(
                (const short*)k + ((size_t)(b * 4096) + n) * 256 + h * 32 + quad * 8);
        }
        #pragma unroll
        for (int t = 0; t < 8; ++t) {
            f32x4 s = __builtin_amdgcn_mfma_f32_16x16x32_bf16(agFrag, kf[t], zero4, 0, 0, 0);
            int n = nbase + t * 16 + ln;
            #pragma unroll
            for (int r = 0; r < 4; ++r) {
                int a = a_row + r;
                float e = 0.f;
                if (a < 49) {
                    float sv = s[r] * SCALE + pbias[((size_t)(h * 49) + a) * 4096 + n];
                    e = __expf(sv);
                }
                sacc[r] += e;
                pLds[(a_row + r) * 140 + t * 16 + ln] = (short)f2bf(e);
            }
        }
        __syncthreads();     // pLds + vtLds ready
        // ---- PV: O[m=a][d] += P . V, K = 128 (4 mfma k-steps)
        #pragma unroll
        for (int ks = 0; ks < 4; ++ks) {
            short8 pf = *reinterpret_cast<const short8*>(&pLds[(w * 16 + ln) * 140 + ks * 32 + quad * 8]);
            #pragma unroll
            for (int dt = 0; dt < 2; ++dt) {
                short8 vf = *reinterpret_cast<const short8*>(&vtLds[(dt * 16 + ln) * 140 + ks * 32 + quad * 8]);
                oAcc[dt] = __builtin_amdgcn_mfma_f32_16x16x32_bf16(pf, vf, oAcc[dt], 0, 0, 0);
            }
        }
    }

    // ---- write partials
    const size_t obase = ((size_t)((b * 8 + h) * 8 + split)) * 1568;
    #pragma unroll
    for (int dt = 0; dt < 2; ++dt)
        #pragma unroll
        for (int r = 0; r < 4; ++r) {
            int a = a_row + r;
            if (a < 49)
                part_O[obase + a * 32 + dt * 16 + ln] = oAcc[dt][r];
        }
    #pragma unroll
    for (int r = 0; r < 4; ++r) {
        float sv = sacc[r];
        #pragma unroll
        for (int m = 1; m < 16; m <<= 1) sv += __shfl_xor(sv, m, 64);
        if (ln == 0) {
            int a = a_row + r;
            if (a < 49)
                part_sum[((b * 8 + h) * 8 + split) * 49 + a] = sv;
        }
    }
}

// K4b: combine split partials -> avT[bh][d][64] bf16 (zero-padded a>=49),
// which is exactly stage2's PV B-fragment layout.  grid 128, block 256.
__global__ __launch_bounds__(256) void stage1_fin(
    const float* __restrict__ part_O, const float* __restrict__ part_sum,
    bf16* __restrict__ avT)
{
    int bh = blockIdx.x;
    __shared__ float inv[49];
    int tid = threadIdx.x;
    if (tid < 49) {
        float s = 0.f;
        #pragma unroll
        for (int sp = 0; sp < 8; ++sp) s += part_sum[(bh * 8 + sp) * 49 + tid];
        inv[tid] = 1.f / s;
    }
    __syncthreads();
    unsigned short* dst = reinterpret_cast<unsigned short*>(avT) + (size_t)bh * 2048;
    for (int i = tid; i < 2048; i += 256) {
        int d = i >> 6, a = i & 63;
        float val = 0.f;
        if (a < 49) {
            float o = 0.f;
            #pragma unroll
            for (int sp = 0; sp < 8; ++sp)
                o += part_O[((size_t)(bh * 8) + sp) * 1568 + a * 32 + d];
            val = o * inv[a];
        }
        dst[i] = f2bf(val);
    }
}

// ---------------------------------------------------------------------------
// K5: stage-2 attention via MFMA + fused depthwise conv, latency-hiding form.
// Per sub: (1) prefetch the 9 dwconv v-tiles into regs, (2) prefetch bias
// (8B/lane/pos from permuted ab2), (3) QK mfma + exp + shfl row-sum,
// (4) P -> wave-private pLds (NO barrier) -> PV mfma, (5) O -> oLds[sub&1]
// (double-buffered), ONE barrier, (6) dwconv consume + 16B mid store.
// grid (128, 16), block 256 (4 waves).
// ---------------------------------------------------------------------------
__global__ __launch_bounds__(256) void stage2_mfma(
    const bf16* __restrict__ q, const bf16* __restrict__ v,
    const float* __restrict__ agent, const bf16* __restrict__ avT,
    const bf16* __restrict__ ab2, const float* __restrict__ wdwc,
    const float* __restrict__ bdwc, bf16* __restrict__ mid)
{
    const int bh = blockIdx.x;
    const int b = bh >> 3, h = bh & 7;
    const int base = blockIdx.y * 256;
    const int tid = threadIdx.x;
    const int w = tid >> 6, lane = tid & 63;
    const int quad = lane >> 4, ln = lane & 15;

    __shared__ __align__(16) short agLds[64 * 32];      // [a][d] bf16, a>=49 zero
    __shared__ __align__(16) short pLds[4][16 * 72];    // per-wave P, row=pos_loc
    __shared__ __align__(16) float oLds[2][64 * 36];    // O transpose, dbuf
    __shared__ float wdLds[32 * 9];
    __shared__ float bdLds[32];

    // stage agents (bf16) + dwconv weights
    for (int i = tid; i < 64 * 32; i += 256) {
        int a = i >> 5, d = i & 31;
        float val = (a < 49) ? agent[((size_t)(b * 49) + a) * 256 + h * 32 + d] : 0.f;
        agLds[i] = (short)f2bf(val);
    }
    for (int i = tid; i < 288; i += 256) wdLds[i] = wdwc[(size_t)(h * 32) * 9 + i];
    if (tid < 32) bdLds[tid] = bdwc[h * 32 + tid];
    __syncthreads();

    // agent B-fragments (rows = a), hoisted
    short8 agF[4];
    #pragma unroll
    for (int t = 0; t < 4; ++t)
        agF[t] = *reinterpret_cast<const short8*>(&agLds[(t * 16 + ln) * 32 + quad * 8]);

    // agent_v B-fragments (rows = d, k over a), hoisted (sub-independent)
    short8 avF[2][2];
    #pragma unroll
    for (int dt = 0; dt < 2; ++dt)
        #pragma unroll
        for (int kc = 0; kc < 2; ++kc)
            avF[dt][kc] = *reinterpret_cast<const short8*>(
                (const short*)avT + ((size_t)bh * 32 + dt * 16 + ln) * 64 + kc * 32 + quad * 8);

    const int prow = tid >> 2, cl = (tid & 3) * 8;   // dwconv mapping
    const f32x4 zero4 = {0.f, 0.f, 0.f, 0.f};

    for (int sub = 0; sub < 4; ++sub) {
        const int p = sub & 1;
        const int pos0w = base + sub * 64 + w * 16;

        // ---- (1) prefetch dwconv v neighborhoods (independent of attention)
        const int posd = base + sub * 64 + prow;
        const int yd = posd >> 6, xd = posd & 63;
        uint4 vpre[9];
        #pragma unroll
        for (int dy = -1; dy <= 1; ++dy)
            #pragma unroll
            for (int dx = -1; dx <= 1; ++dx) {
                int idx = (dy + 1) * 3 + (dx + 1);
                int yy = yd + dy, xx = xd + dx;
                int yc = min(max(yy, 0), 63), xc = min(max(xx, 0), 63);
                uint4 t = *reinterpret_cast<const uint4*>(
                    v + ((size_t)(b * 4096) + yc * 64 + xc) * 256 + h * 32 + cl);
                if ((unsigned)yy >= 64u || (unsigned)xx >= 64u) { t.x = 0; t.y = 0; t.z = 0; t.w = 0; }
                vpre[idx] = t;
            }

        // ---- (2) prefetch bias: one 8B load per pos-row r (permuted ab2)
        uint2 bpre[4];
        #pragma unroll
        for (int r = 0; r < 4; ++r) {
            int posr = pos0w + quad * 4 + r;
            bpre[r] = *reinterpret_cast<const uint2*>(
                reinterpret_cast<const unsigned short*>(ab2) + ((size_t)(h * 4096) + posr) * 64 + ln * 4);
        }

        // ---- (3) S = q . agent^T  (A rows = pos, one K=32 step)
        short8 qf = *reinterpret_cast<const short8*>(
            (const short*)q + ((size_t)(b * 4096) + pos0w + ln) * 256 + h * 32 + quad * 8);
        f32x4 sT[4];
        #pragma unroll
        for (int t = 0; t < 4; ++t)
            sT[t] = __builtin_amdgcn_mfma_f32_16x16x32_bf16(qf, agF[t], zero4, 0, 0, 0);

        // bias + exp + masked row-sum   (a = t*16+ln)
        float e[4][4];
        float part[4] = {0.f, 0.f, 0.f, 0.f};
        #pragma unroll
        for (int r = 0; r < 4; ++r) {
            float bias[4];
            bias[0] = __uint_as_float(bpre[r].x << 16);
            bias[1] = __uint_as_float(bpre[r].x & 0xffff0000u);
            bias[2] = __uint_as_float(bpre[r].y << 16);
            bias[3] = __uint_as_float(bpre[r].y & 0xffff0000u);
            #pragma unroll
            for (int t = 0; t < 4; ++t) {
                int a = t * 16 + ln;
                float ev = 0.f;
                if (a < 49) ev = __expf(sT[t][r] * SCALE + bias[t]);
                e[t][r] = ev;
                part[r] += ev;
            }
        }
        #pragma unroll
        for (int r = 0; r < 4; ++r) {
            #pragma unroll
            for (int m = 1; m < 16; m <<= 1) part[r] += __shfl_xor(part[r], m, 64);
            part[r] = 1.f / part[r];
        }

        // ---- (4) normalized P -> wave-private pLds (A-frag layout), no barrier
        #pragma unroll
        for (int t = 0; t < 4; ++t)
            #pragma unroll
            for (int r = 0; r < 4; ++r)
                pLds[w][(quad * 4 + r) * 72 + t * 16 + ln] = (short)f2bf(e[t][r] * part[r]);

        // O = P . avT^T  (K = 64 over padded a)
        f32x4 oAcc[2] = {};
        #pragma unroll
        for (int kc = 0; kc < 2; ++kc) {
            short8 pf = *reinterpret_cast<const short8*>(&pLds[w][ln * 72 + kc * 32 + quad * 8]);
            #pragma unroll
            for (int dt = 0; dt < 2; ++dt)
                oAcc[dt] = __builtin_amdgcn_mfma_f32_16x16x32_bf16(pf, avF[dt][kc], oAcc[dt], 0, 0, 0);
        }

        // ---- (5) O -> oLds[p] (row = sub-local pos, col = ch_loc)
        #pragma unroll
        for (int dt = 0; dt < 2; ++dt)
            #pragma unroll
            for (int r = 0; r < 4; ++r)
                oLds[p][(w * 16 + quad * 4 + r) * 36 + dt * 16 + ln] = oAcc[dt][r];
        __syncthreads();   // the ONLY barrier per sub (oLds write -> read)

        // ---- (6) dwconv consume + mid write: thread owns posd, 8 ch at cl
        {
            float acc[8];
            #pragma unroll
            for (int j = 0; j < 8; ++j) acc[j] = oLds[p][prow * 36 + cl + j] + bdLds[cl + j];
            #pragma unroll
            for (int idx = 0; idx < 9; ++idx) {
                unsigned int uu[4] = {vpre[idx].x, vpre[idx].y, vpre[idx].z, vpre[idx].w};
                float f[8];
                f[0] = __uint_as_float(uu[0] << 16); f[1] = __uint_as_float(uu[0] & 0xffff0000u);
                f[2] = __uint_as_float(uu[1] << 16); f[3] = __uint_as_float(uu[1] & 0xffff0000u);
                f[4] = __uint_as_float(uu[2] << 16); f[5] = __uint_as_float(uu[2] & 0xffff0000u);
                f[6] = __uint_as_float(uu[3] << 16); f[7] = __uint_as_float(uu[3] & 0xffff0000u);
                #pragma unroll
                for (int j = 0; j < 8; ++j)
                    acc[j] = fmaf(wdLds[(cl + j) * 9 + idx], f[j], acc[j]);
            }
            unsigned short o16[8];
            #pragma unroll
            for (int j = 0; j < 8; ++j) o16[j] = f2bf(acc[j]);
            *reinterpret_cast<uint4*>(mid + ((size_t)(b * 4096) + posd) * 256 + h * 32 + cl) =
                *reinterpret_cast<const uint4*>(o16);
        }
        // next sub writes oLds[1-p]; safe: all waves passed this sub's barrier,
        // which is after the previous read of that buffer.
    }
}

// ---------------------------------------------------------------------------
// K7: proj MFMA GEMM.  D[m=ch][n=pos] = Wp (256x256) . mid[b]^T (256x4096).
// grid (2, 512), block 256.
// ---------------------------------------------------------------------------
__global__ __launch_bounds__(256) void proj_mfma(
    const bf16* __restrict__ mid, const bf16* __restrict__ Wp,
    const float* __restrict__ bp, float* __restrict__ out)
{
    __shared__ __align__(16) short As[128 * 32];
    __shared__ __align__(16) short Bs[128 * 32];
    const int m0 = blockIdx.x * 128;           // ch tile
    const int b  = blockIdx.y >> 5;
    const int n0 = (blockIdx.y & 31) * 128;    // pos tile
    const int tid = threadIdx.x;
    const int w = tid >> 6, lane = tid & 63;
    const int wm = w & 1, wn = w >> 1;
    const int quad = lane >> 4, ln = lane & 15;

    const short* Ag = (const short*)Wp + (size_t)m0 * 256;
    const short* Bg = (const short*)mid + ((size_t)(b * 4096 + n0)) * 256;
    const int ldrow = lane >> 2;
    const int ldcol = (lane & 3) * 8;

    f32x4 acc[4][4] = {};

    for (int k0 = 0; k0 < 256; k0 += 32) {
        __syncthreads();
        #pragma unroll
        for (int p = 0; p < 2; ++p) {
            int row = w * 32 + p * 16;
            gload16(Ag + (size_t)(row + ldrow) * 256 + k0 + ldcol, As + row * 32);
            gload16(Bg + (size_t)(row + ldrow) * 256 + k0 + ldcol, Bs + row * 32);
        }
        __syncthreads();
        short8 af[4], bfr[4];
        #pragma unroll
        for (int mi = 0; mi < 4; ++mi)
            af[mi] = *reinterpret_cast<const short8*>(&As[(wm * 64 + mi * 16 + ln) * 32 + quad * 8]);
        #pragma unroll
        for (int ni = 0; ni < 4; ++ni)
            bfr[ni] = *reinterpret_cast<const short8*>(&Bs[(wn * 64 + ni * 16 + ln) * 32 + quad * 8]);
        #pragma unroll
        for (int mi = 0; mi < 4; ++mi)
            #pragma unroll
            for (int ni = 0; ni < 4; ++ni)
                acc[mi][ni] = __builtin_amdgcn_mfma_f32_16x16x32_bf16(
                    af[mi], bfr[ni], acc[mi][ni], 0, 0, 0);
    }

    #pragma unroll
    for (int mi = 0; mi < 4; ++mi)
        #pragma unroll
        for (int r = 0; r < 4; ++r) {
            int ch = m0 + wm * 64 + mi * 16 + quad * 4 + r;
            float bias = bp[ch];
            float* o = out + ((size_t)(b * 256 + ch)) * 4096 + n0 + wn * 64 + ln;
            #pragma unroll
            for (int ni = 0; ni < 4; ++ni)
                o[ni * 16] = acc[mi][ni][r] + bias;
        }
}

extern "C" void kernel_launch(void* const* d_in, const int* in_sizes, int n_in,
                              void* d_out, int out_size, void* d_ws, size_t ws_size,
                              hipStream_t stream)
{
    const float* x       = (const float*)d_in[0];
    const float* Wq      = (const float*)d_in[1];
    const float* Wkv     = (const float*)d_in[2];
    const float* Wproj   = (const float*)d_in[3];
    const float* bproj   = (const float*)d_in[4];
    const float* Wdwc    = (const float*)d_in[5];
    const float* bdwc    = (const float*)d_in[6];
    const float* an_bias = (const float*)d_in[7];
    const float* na_bias = (const float*)d_in[8];
    const float* ah_bias = (const float*)d_in[9];
    const float* aw_bias = (const float*)d_in[10];
    const float* ha_bias = (const float*)d_in[11];
    const float* wa_bias = (const float*)d_in[12];
    // H=64, W=64 hard-coded (d_in[13], d_in[14])

    char* ws = (char*)d_ws;
    bf16*  q      = (bf16*)(ws + 0);
    bf16*  k      = (bf16*)(ws + 33554432);
    bf16*  v      = (bf16*)(ws + 67108864);
    // the 33.5 MB region at 100663296 is triple-used over time:
    //   1) xT (qkv input), 2) stage1 partials, 3) mid (stage2 out / proj in)
    bf16*  xT     = (bf16*)(ws + 100663296);
    float* part_O   = (float*)(ws + 100663296);
    float* part_sum = (float*)(ws + 100663296 + 6422528);
    bf16*  mid    = (bf16*)(ws + 100663296);
    float* agent  = (float*)(ws + 134217728);
    bf16*  avT    = (bf16*)(ws + 135020544);   // [bh][d][64] bf16, 512 KB
    float* pbias  = (float*)(ws + 135823360);
    bf16*  ab2    = (bf16*)(ws + 142245888);   // [h][pos][64] bf16 (permuted), 4 MB
    bf16*  Wqkv_bf = (bf16*)(ws + 148668416);
    bf16*  Wp_bf   = (bf16*)(ws + 149061632);
    float* out    = (float*)d_out;

    convert_w  <<<dim3(1024),      256, 0, stream>>>(Wq, Wkv, Wproj, Wqkv_bf, Wp_bf);
    x_to_bf16T <<<dim3(64, 4, 16), 256, 0, stream>>>(x, xT);
    qkv_mfma   <<<dim3(512, 6),    256, 0, stream>>>(xT, Wqkv_bf, q, k, v);
    pool_agent <<<dim3(784),       256, 0, stream>>>(q, agent);
    make_pbias <<<dim3(392),       256, 0, stream>>>(an_bias, ah_bias, aw_bias, pbias);
    make_abias2<<<dim3(8, 16),     256, 0, stream>>>(na_bias, ha_bias, wa_bias, ab2);
    stage1     <<<dim3(1024),      256, 0, stream>>>(agent, k, v, pbias, part_O, part_sum);
    stage1_fin <<<dim3(128),       256, 0, stream>>>(part_O, part_sum, avT);
    stage2_mfma<<<dim3(128, 16),   256, 0, stream>>>(q, v, agent, avT, ab2, Wdwc, bdwc, mid);
    proj_mfma  <<<dim3(2, 512),    256, 0, stream>>>(mid, Wp_bf, bproj, out);
}